// Round 4
// baseline (504.341 us; speedup 1.0000x reference)
//
#include <hip/hip_runtime.h>
#include <hip/hip_bf16.h>
#include <type_traits>

using bf16 = __hip_bfloat16;

typedef __bf16 bf16x8 __attribute__((ext_vector_type(8)));
typedef unsigned short u16x8 __attribute__((ext_vector_type(8)));
typedef float f32x4 __attribute__((ext_vector_type(4)));

constexpr int Bdim = 8, Sdim = 2048, Idim = 1024, Hdim = 4096, Odim = 1024;
constexpr int CH = 64;              // scan chunks per sequence
constexpr int CL = Sdim / CH;       // 32 steps per chunk

#define EP_SIGMOID 0
#define EP_RELU    1
#define EP_BIAS    2

__device__ __forceinline__ void async16(void* lds, const void* g) {
    __builtin_amdgcn_global_load_lds(
        (const __attribute__((address_space(1))) unsigned int*)g,
        (__attribute__((address_space(3))) unsigned int*)lds,
        16, 0, 0);
}

// f32 -> bf16 convert; n multiple of 1024; 4 elems/thread
__global__ __launch_bounds__(256) void cvt_f32_bf16(const float* __restrict__ in,
                                                    bf16* __restrict__ out, int n) {
    const int i = (blockIdx.x * 256 + threadIdx.x) * 4;
    if (i >= n) return;
    const float4 v = *(const float4*)(in + i);
    union { unsigned short us[4]; unsigned long long u64; } r;
    r.us[0] = __bfloat16_as_ushort(__float2bfloat16(v.x));
    r.us[1] = __bfloat16_as_ushort(__float2bfloat16(v.y));
    r.us[2] = __bfloat16_as_ushort(__float2bfloat16(v.z));
    r.us[3] = __bfloat16_as_ushort(__float2bfloat16(v.w));
    *(unsigned long long*)(out + i) = r.u64;
}

// load 8 consecutive elements as bf16 (f32 converted in-register)
__device__ __forceinline__ u16x8 load8(const float* p) {
    const float4 v0 = *(const float4*)p;
    const float4 v1 = *(const float4*)(p + 4);
    u16x8 r;
    r[0] = __bfloat16_as_ushort(__float2bfloat16(v0.x));
    r[1] = __bfloat16_as_ushort(__float2bfloat16(v0.y));
    r[2] = __bfloat16_as_ushort(__float2bfloat16(v0.z));
    r[3] = __bfloat16_as_ushort(__float2bfloat16(v0.w));
    r[4] = __bfloat16_as_ushort(__float2bfloat16(v1.x));
    r[5] = __bfloat16_as_ushort(__float2bfloat16(v1.y));
    r[6] = __bfloat16_as_ushort(__float2bfloat16(v1.z));
    r[7] = __bfloat16_as_ushort(__float2bfloat16(v1.w));
    return r;
}
__device__ __forceinline__ u16x8 load8(const bf16* p) { return *(const u16x8*)p; }

__device__ __forceinline__ float toF(float v) { return v; }
__device__ __forceinline__ float toF(bf16 v)  { return __bfloat162float(v); }

// vectorized 4-wide loads for the scan kernels (G13: scalar bf16 = 2x loss)
__device__ __forceinline__ void ld4(const bf16* p, float f[4]) {
    const ushort4 v = *(const ushort4*)p;
    f[0] = __bfloat162float(__builtin_bit_cast(bf16, v.x));
    f[1] = __bfloat162float(__builtin_bit_cast(bf16, v.y));
    f[2] = __bfloat162float(__builtin_bit_cast(bf16, v.z));
    f[3] = __bfloat162float(__builtin_bit_cast(bf16, v.w));
}
__device__ __forceinline__ void ld4(const float* p, float f[4]) {
    const float4 v = *(const float4*)p;
    f[0] = v.x; f[1] = v.y; f[2] = v.z; f[3] = v.w;
}

// ---------------------------------------------------------------------------
// Legacy 128x128 GEMM (kept for the no-workspace fallback path)
// ---------------------------------------------------------------------------
template <int MODE, int N, int K, typename TA, typename TB, typename TO>
__global__ __launch_bounds__(256) void gemm_bt(const TA* __restrict__ A,
                                               const TB* __restrict__ Bm,
                                               const float* __restrict__ bias,
                                               TO* __restrict__ outp,
                                               int Mt) {
    __shared__ __align__(16) unsigned short Alds[128 * 32];
    __shared__ __align__(16) unsigned short Blds[128 * 32];

    const int tid  = threadIdx.x;
    const int lane = tid & 63;
    const int wave = tid >> 6;
    const int wr = wave >> 1, wc = wave & 1;
    const int quad = lane >> 4, l15 = lane & 15;

    constexpr int Nt = N >> 7;
    constexpr int GRP = 8;
    constexpr int gsz = GRP * Nt;
    const int g   = blockIdx.x / gsz;
    const int rem = blockIdx.x - g * gsz;
    const int mbase = g * GRP;
    int msz = Mt - mbase; if (msz > GRP) msz = GRP;
    const int m_idx = mbase + rem % msz;
    const int n_idx = rem / msz;
    const int m0 = m_idx * 128;
    const int n0 = n_idx * 128;

    const int srow = tid >> 2;
    const int scol = (tid & 3) * 8;
    const TA* ag0 = A  + (size_t)(m0 + srow) * K + scol;
    const TA* ag1 = ag0 + (size_t)64 * K;
    const TB* bg0 = Bm + (size_t)(n0 + srow) * K + scol;
    const TB* bg1 = bg0 + (size_t)64 * K;
    unsigned short* al0 = Alds + tid * 8;
    unsigned short* al1 = al0 + 2048;
    unsigned short* bl0 = Blds + tid * 8;
    unsigned short* bl1 = bl0 + 2048;

    f32x4 acc[4][4];
#pragma unroll
    for (int i = 0; i < 4; ++i)
#pragma unroll
        for (int j = 0; j < 4; ++j) acc[i][j] = {0.f, 0.f, 0.f, 0.f};

    constexpr bool FAST = std::is_same_v<TA, bf16> && std::is_same_v<TB, bf16>;

#pragma unroll 8
    for (int k0 = 0; k0 < K; k0 += 32) {
        if constexpr (FAST) {
            async16(al0, ag0); async16(al1, ag1);
            async16(bl0, bg0); async16(bl1, bg1);
        } else {
            const u16x8 a0 = load8(ag0), a1 = load8(ag1);
            const u16x8 b0 = load8(bg0), b1 = load8(bg1);
            *(u16x8*)al0 = a0; *(u16x8*)al1 = a1;
            *(u16x8*)bl0 = b0; *(u16x8*)bl1 = b1;
        }
        ag0 += 32; ag1 += 32; bg0 += 32; bg1 += 32;
        __syncthreads();

        bf16x8 af[4], bfv[4];
#pragma unroll
        for (int mi = 0; mi < 4; ++mi) {
            const u16x8 t = *(const u16x8*)(Alds + (wr * 64 + mi * 16 + l15) * 32 + quad * 8);
            af[mi] = __builtin_bit_cast(bf16x8, t);
        }
#pragma unroll
        for (int ni = 0; ni < 4; ++ni) {
            const u16x8 t = *(const u16x8*)(Blds + (wc * 64 + ni * 16 + l15) * 32 + quad * 8);
            bfv[ni] = __builtin_bit_cast(bf16x8, t);
        }
#pragma unroll
        for (int mi = 0; mi < 4; ++mi)
#pragma unroll
            for (int ni = 0; ni < 4; ++ni)
                acc[mi][ni] = __builtin_amdgcn_mfma_f32_16x16x32_bf16(af[mi], bfv[ni], acc[mi][ni], 0, 0, 0);
        __syncthreads();
    }

#pragma unroll
    for (int ni = 0; ni < 4; ++ni) {
        const int ncol = n0 + wc * 64 + ni * 16 + l15;
        const float bv = bias[ncol];
#pragma unroll
        for (int mi = 0; mi < 4; ++mi) {
            const int mrow = m0 + wr * 64 + mi * 16 + quad * 4;
#pragma unroll
            for (int r = 0; r < 4; ++r) {
                float v = acc[mi][ni][r] + bv;
                if constexpr (MODE == EP_SIGMOID) v = 1.f / (1.f + __expf(-v));
                if constexpr (MODE == EP_RELU)    v = v > 0.f ? v : 0.f;
                if constexpr (std::is_same_v<TO, bf16>)
                    outp[(size_t)(mrow + r) * N + ncol] = __float2bfloat16(v);
                else
                    outp[(size_t)(mrow + r) * N + ncol] = v;
            }
        }
    }
}

// ---------------------------------------------------------------------------
// 8-phase BMx256 GEMM, SINGLE barrier per phase (pre-MFMA only).
// C = A * B^T, B row-major [N][K].
// Phase layout per K-tile (quadrants (aLo.b01)(aLo.b23)(aHi.b01)(aHi.b23)):
//   p1: read aLo+b01(t); stage A0(t+1)->AN | bar | MFMA
//   p2: read b23(t);     stage A1(t+1)->AN | bar | MFMA
//   p3: read aHi(t);                       | bar | MFMA
//   p4: stage B0+B1(t+2)->BB; vmcnt(4)     | bar | MFMA (zero-wait)
// Dropping the post-MFMA barrier lets wave X run phase p+1 reads/stages under
// wave Y's phase-p MFMA (read time hides under the matrix pipe). Hazard
// ledger: every stage targets a region whose last readers consumed their
// ds_reads via their own MFMA's lgkm wait BEFORE arriving at the barrier the
// stager has passed (B-stages deferred to p4 so b23(p2) is consumed first).
// vmcnt(4) at p4 retires B(t+1)+A(t+1) before tile t+1 reads them (holds for
// LA=1 and LA=2). Epilogue ni-innermost (write-combining, r3-proven).
// ---------------------------------------------------------------------------
template <int MODE, int BM, int N, int K, typename TO>
__global__ __launch_bounds__(512, 2) void gemm8p(const bf16* __restrict__ A,
                                                 const bf16* __restrict__ Bm,
                                                 const float* __restrict__ bias,
                                                 TO* __restrict__ outp,
                                                 int Mt) {
    static_assert(BM == 256 || BM == 128);
    constexpr int MR   = BM / 32;        // m-frags per wave (8 or 4)
    constexpr int MR2  = MR / 2;
    constexpr int ABUF = BM * 128;       // bytes per A buffer
    constexpr int BBUF = 256 * 128;      // 32 KB per B buffer
    constexpr int HALF_A = ABUF / 2;
    constexpr int HALF_B = BBUF / 2;     // 16 KB
    constexpr int LA = BM / 128;         // A global_load_lds per thread per half
    constexpr int NT = K / 64;
    static_assert(NT % 2 == 0 && NT >= 2);

    __shared__ __align__(16) char lds[2 * ABUF + 2 * BBUF];

    const int tid  = threadIdx.x;
    const int lane = tid & 63;
    const int wave = tid >> 6;
    const int wr = wave >> 2;            // 0..1
    const int wc = wave & 3;             // 0..3
    const int quad = lane >> 4, l15 = lane & 15;

    // grid: m-fastest rasterization + bijective XCD chunk swizzle
    constexpr int Nt = N / 256;
    const int nwg = Mt * Nt;
    int b = blockIdx.x;
    if ((nwg & 7) == 0) { const int cpx = nwg >> 3; b = (b & 7) * cpx + (b >> 3); }
    const int m_idx = b % Mt;
    const int n_idx = b / Mt;
    const int m0 = m_idx * BM;
    const int n0 = n_idx * 256;

    // swizzled lane offset for fragment ds_read_b128 (within 1024B subtile)
    const int loff = (l15 * 64 + quad * 16) ^ ((l15 >> 3) << 5);

    char* const Ab0 = lds;
    char* const Ab1 = lds + ABUF;
    char* const Bb0 = lds + 2 * ABUF;
    char* const Bb1 = lds + 2 * ABUF + BBUF;

    // staging coords: linear LDS chunk s -> inverse-swizzled global (row,k)
    int rowS[2], klS[2];
#pragma unroll
    for (int l = 0; l < 2; ++l) {
        const int s = l * 512 + tid;
        const int c = s & 63;                         // 16B chunk in subtile
        const int e = c ^ (((c >> 5) & 1) << 1);      // unswizzle
        rowS[l] = ((s >> 7) << 4) + (e >> 2);
        klS[l]  = ((s >> 6) & 1) * 32 + (e & 3) * 8;
    }
    const bf16* pa[2]; const bf16* pb[2];
#pragma unroll
    for (int l = 0; l < 2; ++l) {
        pa[l] = A  + (size_t)(m0 + rowS[l]) * K + klS[l];
        pb[l] = Bm + (size_t)(n0 + rowS[l]) * K + klS[l];
    }

    auto stageA = [&](char* dst, int h, int kt) {
#pragma unroll
        for (int l = 0; l < LA; ++l)
            async16(dst + h * HALF_A + (l * 512 + tid) * 16,
                    pa[l] + (size_t)h * (BM / 2) * K + (size_t)kt * 64);
    };
    auto stageB = [&](char* dst, int h, int kt) {
#pragma unroll
        for (int l = 0; l < 2; ++l)
            async16(dst + h * HALF_B + (l * 512 + tid) * 16,
                    pb[l] + (size_t)h * 128 * K + (size_t)kt * 64);
    };
    auto ldA = [&](const char* abase, int mi_g, int ks) -> bf16x8 {
        return __builtin_bit_cast(bf16x8,
            *(const u16x8*)(abase + (((wr * MR + mi_g) * 2 + ks) << 10) + loff));
    };
    auto ldB = [&](const char* bbase, int ni, int ks) -> bf16x8 {
        return __builtin_bit_cast(bf16x8,
            *(const u16x8*)(bbase + (((wc * 4 + ni) * 2 + ks) << 10) + loff));
    };

    f32x4 acc[MR][4];
#pragma unroll
    for (int i = 0; i < MR; ++i)
#pragma unroll
        for (int j = 0; j < 4; ++j) acc[i][j] = {0.f, 0.f, 0.f, 0.f};
    bf16x8 a[MR2][2], bb[4][2];

    // prologue: A(0), B(0), B(1); vmcnt(4) retires A(0)+B(0), leaves B(1)
    stageA(Ab0, 0, 0); stageA(Ab0, 1, 0);
    stageB(Bb0, 0, 0); stageB(Bb0, 1, 0);
    stageB(Bb1, 0, 1); stageB(Bb1, 1, 1);
    asm volatile("s_waitcnt vmcnt(4)" ::: "memory");
    __builtin_amdgcn_s_barrier();

#define FENCE() asm volatile("" ::: "memory")
#define MFMA_Q(AR, NI0)                                                         \
    _Pragma("unroll") for (int mi = 0; mi < MR2; ++mi)                          \
    _Pragma("unroll") for (int ni = 0; ni < 2; ++ni)                            \
    _Pragma("unroll") for (int ks = 0; ks < 2; ++ks)                            \
        acc[(AR) + mi][(NI0) + ni] = __builtin_amdgcn_mfma_f32_16x16x32_bf16(   \
            a[mi][ks], bb[(NI0) + ni][ks], acc[(AR) + mi][(NI0) + ni], 0, 0, 0);

#define KTILE(T, AB, BB, AN)                                                    \
    {                                                                           \
        const int t_ = (T);                                                     \
        /* p1: read aLo(t)+b01(t); stage A0(t+1) */                             \
        _Pragma("unroll") for (int mi = 0; mi < MR2; ++mi)                      \
        _Pragma("unroll") for (int ks = 0; ks < 2; ++ks)                        \
            a[mi][ks] = ldA(AB, mi, ks);                                        \
        _Pragma("unroll") for (int ni = 0; ni < 2; ++ni)                        \
        _Pragma("unroll") for (int ks = 0; ks < 2; ++ks)                        \
            bb[ni][ks] = ldB(BB, ni, ks);                                       \
        if (t_ + 1 < NT) stageA(AN, 0, t_ + 1);                                 \
        FENCE(); __builtin_amdgcn_s_barrier(); FENCE();                         \
        __builtin_amdgcn_s_setprio(1);                                          \
        MFMA_Q(0, 0)                                                            \
        __builtin_amdgcn_s_setprio(0);                                          \
        /* p2: read b23(t); stage A1(t+1) */                                    \
        _Pragma("unroll") for (int ni = 0; ni < 2; ++ni)                        \
        _Pragma("unroll") for (int ks = 0; ks < 2; ++ks)                        \
            bb[2 + ni][ks] = ldB(BB, 2 + ni, ks);                               \
        if (t_ + 1 < NT) stageA(AN, 1, t_ + 1);                                 \
        FENCE(); __builtin_amdgcn_s_barrier(); FENCE();                         \
        __builtin_amdgcn_s_setprio(1);                                          \
        MFMA_Q(0, 2)                                                            \
        __builtin_amdgcn_s_setprio(0);                                          \
        /* p3: read aHi(t) */                                                   \
        _Pragma("unroll") for (int mi = 0; mi < MR2; ++mi)                      \
        _Pragma("unroll") for (int ks = 0; ks < 2; ++ks)                        \
            a[mi][ks] = ldA(AB, MR2 + mi, ks);                                  \
        FENCE(); __builtin_amdgcn_s_barrier(); FENCE();                         \
        __builtin_amdgcn_s_setprio(1);                                          \
        MFMA_Q(MR2, 0)                                                          \
        __builtin_amdgcn_s_setprio(0);                                          \
        /* p4: stage B0+B1(t+2); counted vmcnt; zero-wait MFMA */               \
        if (t_ + 2 < NT) { stageB(BB, 0, t_ + 2); stageB(BB, 1, t_ + 2); }      \
        if (t_ + 2 < NT) { asm volatile("s_waitcnt vmcnt(4)" ::: "memory"); }   \
        else             { asm volatile("s_waitcnt vmcnt(0)" ::: "memory"); }   \
        FENCE(); __builtin_amdgcn_s_barrier(); FENCE();                         \
        __builtin_amdgcn_s_setprio(1);                                          \
        MFMA_Q(MR2, 2)                                                          \
        __builtin_amdgcn_s_setprio(0);                                          \
    }

#pragma unroll 1
    for (int t = 0; t < NT; t += 2) {
        KTILE(t,     Ab0, Bb0, Ab1)
        KTILE(t + 1, Ab1, Bb1, Ab0)
    }
#undef KTILE
#undef MFMA_Q
#undef FENCE

    // epilogue: D row = quad*4 + r, col = l15 (verified m89/m91 mapping)
    // ni-innermost: 4 consecutive stores complete one 128B line per wave-row.
    float bv[4];
#pragma unroll
    for (int ni = 0; ni < 4; ++ni) bv[ni] = bias[n0 + wc * 64 + ni * 16 + l15];
#pragma unroll
    for (int mi = 0; mi < MR; ++mi) {
        const int mrow = m0 + wr * (MR * 16) + mi * 16 + quad * 4;
#pragma unroll
        for (int r = 0; r < 4; ++r) {
            TO* rowp = outp + (size_t)(mrow + r) * N + n0 + wc * 64 + l15;
#pragma unroll
            for (int ni = 0; ni < 4; ++ni) {
                float v = acc[mi][ni][r] + bv[ni];
                if constexpr (MODE == EP_SIGMOID) v = 1.f / (1.f + __expf(-v));
                if constexpr (MODE == EP_RELU)    v = v > 0.f ? v : 0.f;
                if constexpr (std::is_same_v<TO, bf16>)
                    rowp[ni * 16] = __float2bfloat16(v);
                else
                    rowp[ni * 16] = v;
            }
        }
    }
}

// phase 1: per-chunk affine coefficients  buf_out = P*buf_in + Q
// 4 elems/thread, vectorized 8B loads (G13)
template <typename XT>
__global__ __launch_bounds__(256) void scan_p1(const XT* __restrict__ x,
                                               const bf16* __restrict__ decay,
                                               float* __restrict__ P,
                                               float* __restrict__ Q) {
    const int bc = blockIdx.x;           // b*CH + c
    const int c = bc & (CH - 1);
    const int b = bc / CH;
    const int i = threadIdx.x * 4;
    size_t idx = ((size_t)(b * Sdim + c * CL)) * Idim + i;
    float p[4] = {1.f, 1.f, 1.f, 1.f};
    float q[4] = {0.f, 0.f, 0.f, 0.f};
#pragma unroll 4
    for (int j = 0; j < CL; ++j) {
        float d[4], xx[4];
        ld4(decay + idx, d);
        ld4(x + idx, xx);
#pragma unroll
        for (int k = 0; k < 4; ++k) {
            q[k] = q[k] * d[k] + (1.f - d[k]) * xx[k];
            p[k] *= d[k];
        }
        idx += Idim;
    }
    *(float4*)(P + (size_t)bc * Idim + i) = {p[0], p[1], p[2], p[3]};
    *(float4*)(Q + (size_t)bc * Idim + i) = {q[0], q[1], q[2], q[3]};
}

// phase 2: sequential combine across chunks (tiny)
__global__ __launch_bounds__(256) void scan_p2(const float* __restrict__ P,
                                               const float* __restrict__ Q,
                                               float* __restrict__ buf0,
                                               int G) {
    const int g = blockIdx.x * 256 + threadIdx.x;
    const int b = g >> 10;
    const int i = g & (Idim - 1);
    if (b >= G) return;
    float buf = 0.f;
    for (int c = 0; c < CH; ++c) {
        const size_t o = ((size_t)(b * CH + c)) * Idim + i;
        buf0[o] = buf;
        buf = P[o] * buf + Q[o];
    }
}

// phase 3: replay with correct init, write combined = x*d + buf (bf16)
// 4 elems/thread, vectorized loads + 8B stores
template <typename XT>
__global__ __launch_bounds__(256) void scan_p3(const XT* __restrict__ x,
                                               const bf16* __restrict__ decay,
                                               const float* __restrict__ buf0,
                                               bf16* __restrict__ comb) {
    const int bc = blockIdx.x;
    const int c = bc & (CH - 1);
    const int b = bc / CH;
    const int i = threadIdx.x * 4;
    size_t idx = ((size_t)(b * Sdim + c * CL)) * Idim + i;
    float buf[4];
    {
        const float4 v = *(const float4*)(buf0 + (size_t)bc * Idim + i);
        buf[0] = v.x; buf[1] = v.y; buf[2] = v.z; buf[3] = v.w;
    }
#pragma unroll 4
    for (int j = 0; j < CL; ++j) {
        float d[4], xx[4];
        ld4(decay + idx, d);
        ld4(x + idx, xx);
        ushort4 o;
#pragma unroll
        for (int k = 0; k < 4; ++k)
            buf[k] = buf[k] * d[k] + (1.f - d[k]) * xx[k];
        o.x = __bfloat16_as_ushort(__float2bfloat16(xx[0] * d[0] + buf[0]));
        o.y = __bfloat16_as_ushort(__float2bfloat16(xx[1] * d[1] + buf[1]));
        o.z = __bfloat16_as_ushort(__float2bfloat16(xx[2] * d[2] + buf[2]));
        o.w = __bfloat16_as_ushort(__float2bfloat16(xx[3] * d[3] + buf[3]));
        *(ushort4*)(comb + idx) = o;
        idx += Idim;
    }
}

extern "C" void kernel_launch(void* const* d_in, const int* in_sizes, int n_in,
                              void* d_out, int out_size, void* d_ws, size_t ws_size,
                              hipStream_t stream) {
    const float* x  = (const float*)d_in[0];
    const float* W1 = (const float*)d_in[1];
    const float* b1 = (const float*)d_in[2];
    const float* W2 = (const float*)d_in[3];
    const float* b2 = (const float*)d_in[4];
    const float* Wg = (const float*)d_in[5];
    const float* bg = (const float*)d_in[6];
    float* out = (float*)d_out;                       // output is f32

    const dim3 blk(256);
    const dim3 blk512(512);

    const size_t nW1 = (size_t)Hdim * Idim;
    const size_t nW2 = (size_t)Odim * Hdim;
    const size_t nWg = (size_t)Idim * Idim;
    const size_t wCopies = (nW1 + nW2 + nWg) * 2;     // 18.9 MB

    const size_t xbB   = (size_t)Sdim * Idim * 2;     // per-batch bf16 x: 4 MB
    const size_t dB    = xbB;                         // decay: 4 MB
    const size_t cmbB  = xbB;                         // comb: 4 MB
    const size_t pB    = (size_t)CH * Idim * 4;       // 256 KB
    const size_t perBatch = xbB + dB + cmbB + 3 * pB; // 12.75 MB

    int G = 0;                                         // 0 = fallback mode
    if (ws_size >= wCopies + 8 * perBatch) G = 8;
    else if (ws_size >= wCopies + 4 * perBatch) G = 4;
    else if (ws_size >= wCopies + 2 * perBatch) G = 2;
    else if (ws_size >= wCopies + 1 * perBatch) G = 1;

    if (G > 0) {
        // ---------- fast path: bf16 copies + 8-phase GEMMs ----------
        char* p = (char*)d_ws;
        bf16* W1b = (bf16*)p;  p += nW1 * 2;
        bf16* W2b = (bf16*)p;  p += nW2 * 2;
        bf16* Wgb = (bf16*)p;  p += nWg * 2;
        bf16*  xb   = (bf16*)p;
        bf16*  decay= (bf16*)(p + (size_t)G * xbB);
        bf16*  comb = (bf16*)(p + (size_t)G * (xbB + dB));
        float* P    = (float*)(p + (size_t)G * (xbB + dB + cmbB));
        float* Q    = (float*)(p + (size_t)G * (xbB + dB + cmbB + pB));
        float* buf0 = (float*)(p + (size_t)G * (xbB + dB + cmbB + 2 * pB));
        bf16*  hid  = xb;                 // reuses xb+decay (G*8MB) after scan
        const int chunk_rows = G * 1024;  // hid = chunk_rows*Hdim*2 = G*8MB

        cvt_f32_bf16<<<(int)(nW1 / 1024), blk, 0, stream>>>(W1, W1b, (int)nW1);
        cvt_f32_bf16<<<(int)(nW2 / 1024), blk, 0, stream>>>(W2, W2b, (int)nW2);
        cvt_f32_bf16<<<(int)(nWg / 1024), blk, 0, stream>>>(Wg, Wgb, (int)nWg);

        for (int b0 = 0; b0 < Bdim; b0 += G) {
            const float* xg = x + (size_t)b0 * Sdim * Idim;
            const int rowsG = G * Sdim;
            const int nXg = rowsG * Idim;

            cvt_f32_bf16<<<nXg / 1024, blk, 0, stream>>>(xg, xb, nXg);

            gemm8p<EP_SIGMOID, 256, Idim, Idim, bf16>
                <<<(rowsG / 256) * (Idim / 256), blk512, 0, stream>>>(
                    xb, Wgb, bg, decay, rowsG / 256);

            scan_p1<bf16><<<G * CH, blk, 0, stream>>>(xb, decay, P, Q);
            scan_p2<<<G * Idim / 256, blk, 0, stream>>>(P, Q, buf0, G);
            scan_p3<bf16><<<G * CH, blk, 0, stream>>>(xb, decay, buf0, comb);

            for (int r0 = 0; r0 < rowsG; r0 += chunk_rows) {
                const int rows = (rowsG - r0 < chunk_rows) ? rowsG - r0 : chunk_rows;
                gemm8p<EP_RELU, 256, Hdim, Idim, bf16>
                    <<<(rows / 256) * (Hdim / 256), blk512, 0, stream>>>(
                        comb + (size_t)r0 * Idim, W1b, b1, hid, rows / 256);
                gemm8p<EP_BIAS, 128, Odim, Hdim, float>
                    <<<(rows / 128) * (Odim / 256), blk512, 0, stream>>>(
                        hid, W2b, b2, out + (size_t)(b0 * Sdim + r0) * Odim, rows / 128);
            }
        }
    } else {
        // ---------- fallback: no copies, in-register f32->bf16 ----------
        char* p = (char*)d_ws;
        bf16*  decay= (bf16*)p;
        bf16*  comb = (bf16*)(p + dB);
        float* P    = (float*)(p + dB + cmbB);
        float* Q    = (float*)(p + dB + cmbB + pB);
        float* buf0 = (float*)(p + dB + cmbB + 2 * pB);
        char*  hp   = p + dB + cmbB + 3 * pB;
        size_t rem  = (ws_size > (size_t)(hp - (char*)d_ws))
                        ? ws_size - (size_t)(hp - (char*)d_ws) : 0;
        int chunk_rows = (int)((rem / ((size_t)Hdim * 2)) / 128) * 128;
        if (chunk_rows < 128) chunk_rows = 128;
        if (chunk_rows > Sdim) chunk_rows = Sdim;
        bf16* hid = (bf16*)hp;

        for (int b0 = 0; b0 < Bdim; ++b0) {
            const float* xg = x + (size_t)b0 * Sdim * Idim;

            gemm_bt<EP_SIGMOID, Idim, Idim, float, float, bf16>
                <<<(Idim / 128) * (Sdim / 128), blk, 0, stream>>>(
                    xg, Wg, bg, decay, Sdim / 128);

            scan_p1<float><<<CH, blk, 0, stream>>>(xg, decay, P, Q);
            scan_p2<<<Idim / 256, blk, 0, stream>>>(P, Q, buf0, 1);
            scan_p3<float><<<CH, blk, 0, stream>>>(xg, decay, buf0, comb);

            for (int r0 = 0; r0 < Sdim; r0 += chunk_rows) {
                const int rows = (Sdim - r0 < chunk_rows) ? Sdim - r0 : chunk_rows;
                gemm_bt<EP_RELU, Hdim, Idim, bf16, float, bf16>
                    <<<(Hdim / 128) * (rows / 128), blk, 0, stream>>>(
                        comb + (size_t)r0 * Idim, W1, b1, hid, rows / 128);
                gemm_bt<EP_BIAS, Odim, Hdim, bf16, float, float>
                    <<<(Odim / 128) * (rows / 128), blk, 0, stream>>>(
                        hid, W2, b2, out + (size_t)(b0 * Sdim + r0) * Odim, rows / 128);
            }
        }
    }
}

// Round 5
// 480.410 us; speedup vs baseline: 1.0498x; 1.0498x over previous
//
#include <hip/hip_runtime.h>
#include <hip/hip_bf16.h>
#include <type_traits>

using bf16 = __hip_bfloat16;

typedef __bf16 bf16x8 __attribute__((ext_vector_type(8)));
typedef unsigned short u16x8 __attribute__((ext_vector_type(8)));
typedef float f32x4 __attribute__((ext_vector_type(4)));

constexpr int Bdim = 8, Sdim = 2048, Idim = 1024, Hdim = 4096, Odim = 1024;
constexpr int CH = 128;             // scan chunks per sequence (r5: 64->128 for occupancy)
constexpr int CL = Sdim / CH;       // 16 steps per chunk

#define EP_SIGMOID 0
#define EP_RELU    1
#define EP_BIAS    2

__device__ __forceinline__ void async16(void* lds, const void* g) {
    __builtin_amdgcn_global_load_lds(
        (const __attribute__((address_space(1))) unsigned int*)g,
        (__attribute__((address_space(3))) unsigned int*)lds,
        16, 0, 0);
}

// f32 -> bf16 convert; n multiple of 1024; 4 elems/thread
__global__ __launch_bounds__(256) void cvt_f32_bf16(const float* __restrict__ in,
                                                    bf16* __restrict__ out, int n) {
    const int i = (blockIdx.x * 256 + threadIdx.x) * 4;
    if (i >= n) return;
    const float4 v = *(const float4*)(in + i);
    union { unsigned short us[4]; unsigned long long u64; } r;
    r.us[0] = __bfloat16_as_ushort(__float2bfloat16(v.x));
    r.us[1] = __bfloat16_as_ushort(__float2bfloat16(v.y));
    r.us[2] = __bfloat16_as_ushort(__float2bfloat16(v.z));
    r.us[3] = __bfloat16_as_ushort(__float2bfloat16(v.w));
    *(unsigned long long*)(out + i) = r.u64;
}

// load 8 consecutive elements as bf16 (f32 converted in-register)
__device__ __forceinline__ u16x8 load8(const float* p) {
    const float4 v0 = *(const float4*)p;
    const float4 v1 = *(const float4*)(p + 4);
    u16x8 r;
    r[0] = __bfloat16_as_ushort(__float2bfloat16(v0.x));
    r[1] = __bfloat16_as_ushort(__float2bfloat16(v0.y));
    r[2] = __bfloat16_as_ushort(__float2bfloat16(v0.z));
    r[3] = __bfloat16_as_ushort(__float2bfloat16(v0.w));
    r[4] = __bfloat16_as_ushort(__float2bfloat16(v1.x));
    r[5] = __bfloat16_as_ushort(__float2bfloat16(v1.y));
    r[6] = __bfloat16_as_ushort(__float2bfloat16(v1.z));
    r[7] = __bfloat16_as_ushort(__float2bfloat16(v1.w));
    return r;
}
__device__ __forceinline__ u16x8 load8(const bf16* p) { return *(const u16x8*)p; }

__device__ __forceinline__ float toF(float v) { return v; }
__device__ __forceinline__ float toF(bf16 v)  { return __bfloat162float(v); }

// vectorized 4-wide loads for the scan kernels (G13: scalar bf16 = 2x loss)
__device__ __forceinline__ void ld4(const bf16* p, float f[4]) {
    const ushort4 v = *(const ushort4*)p;
    f[0] = __bfloat162float(__builtin_bit_cast(bf16, v.x));
    f[1] = __bfloat162float(__builtin_bit_cast(bf16, v.y));
    f[2] = __bfloat162float(__builtin_bit_cast(bf16, v.z));
    f[3] = __bfloat162float(__builtin_bit_cast(bf16, v.w));
}
__device__ __forceinline__ void ld4(const float* p, float f[4]) {
    const float4 v = *(const float4*)p;
    f[0] = v.x; f[1] = v.y; f[2] = v.z; f[3] = v.w;
}

// ---------------------------------------------------------------------------
// Legacy 128x128 GEMM (kept for the no-workspace fallback path)
// ---------------------------------------------------------------------------
template <int MODE, int N, int K, typename TA, typename TB, typename TO>
__global__ __launch_bounds__(256) void gemm_bt(const TA* __restrict__ A,
                                               const TB* __restrict__ Bm,
                                               const float* __restrict__ bias,
                                               TO* __restrict__ outp,
                                               int Mt) {
    __shared__ __align__(16) unsigned short Alds[128 * 32];
    __shared__ __align__(16) unsigned short Blds[128 * 32];

    const int tid  = threadIdx.x;
    const int lane = tid & 63;
    const int wave = tid >> 6;
    const int wr = wave >> 1, wc = wave & 1;
    const int quad = lane >> 4, l15 = lane & 15;

    constexpr int Nt = N >> 7;
    constexpr int GRP = 8;
    constexpr int gsz = GRP * Nt;
    const int g   = blockIdx.x / gsz;
    const int rem = blockIdx.x - g * gsz;
    const int mbase = g * GRP;
    int msz = Mt - mbase; if (msz > GRP) msz = GRP;
    const int m_idx = mbase + rem % msz;
    const int n_idx = rem / msz;
    const int m0 = m_idx * 128;
    const int n0 = n_idx * 128;

    const int srow = tid >> 2;
    const int scol = (tid & 3) * 8;
    const TA* ag0 = A  + (size_t)(m0 + srow) * K + scol;
    const TA* ag1 = ag0 + (size_t)64 * K;
    const TB* bg0 = Bm + (size_t)(n0 + srow) * K + scol;
    const TB* bg1 = bg0 + (size_t)64 * K;
    unsigned short* al0 = Alds + tid * 8;
    unsigned short* al1 = al0 + 2048;
    unsigned short* bl0 = Blds + tid * 8;
    unsigned short* bl1 = bl0 + 2048;

    f32x4 acc[4][4];
#pragma unroll
    for (int i = 0; i < 4; ++i)
#pragma unroll
        for (int j = 0; j < 4; ++j) acc[i][j] = {0.f, 0.f, 0.f, 0.f};

    constexpr bool FAST = std::is_same_v<TA, bf16> && std::is_same_v<TB, bf16>;

#pragma unroll 8
    for (int k0 = 0; k0 < K; k0 += 32) {
        if constexpr (FAST) {
            async16(al0, ag0); async16(al1, ag1);
            async16(bl0, bg0); async16(bl1, bg1);
        } else {
            const u16x8 a0 = load8(ag0), a1 = load8(ag1);
            const u16x8 b0 = load8(bg0), b1 = load8(bg1);
            *(u16x8*)al0 = a0; *(u16x8*)al1 = a1;
            *(u16x8*)bl0 = b0; *(u16x8*)bl1 = b1;
        }
        ag0 += 32; ag1 += 32; bg0 += 32; bg1 += 32;
        __syncthreads();

        bf16x8 af[4], bfv[4];
#pragma unroll
        for (int mi = 0; mi < 4; ++mi) {
            const u16x8 t = *(const u16x8*)(Alds + (wr * 64 + mi * 16 + l15) * 32 + quad * 8);
            af[mi] = __builtin_bit_cast(bf16x8, t);
        }
#pragma unroll
        for (int ni = 0; ni < 4; ++ni) {
            const u16x8 t = *(const u16x8*)(Blds + (wc * 64 + ni * 16 + l15) * 32 + quad * 8);
            bfv[ni] = __builtin_bit_cast(bf16x8, t);
        }
#pragma unroll
        for (int mi = 0; mi < 4; ++mi)
#pragma unroll
            for (int ni = 0; ni < 4; ++ni)
                acc[mi][ni] = __builtin_amdgcn_mfma_f32_16x16x32_bf16(af[mi], bfv[ni], acc[mi][ni], 0, 0, 0);
        __syncthreads();
    }

#pragma unroll
    for (int ni = 0; ni < 4; ++ni) {
        const int ncol = n0 + wc * 64 + ni * 16 + l15;
        const float bv = bias[ncol];
#pragma unroll
        for (int mi = 0; mi < 4; ++mi) {
            const int mrow = m0 + wr * 64 + mi * 16 + quad * 4;
#pragma unroll
            for (int r = 0; r < 4; ++r) {
                float v = acc[mi][ni][r] + bv;
                if constexpr (MODE == EP_SIGMOID) v = 1.f / (1.f + __expf(-v));
                if constexpr (MODE == EP_RELU)    v = v > 0.f ? v : 0.f;
                if constexpr (std::is_same_v<TO, bf16>)
                    outp[(size_t)(mrow + r) * N + ncol] = __float2bfloat16(v);
                else
                    outp[(size_t)(mrow + r) * N + ncol] = v;
            }
        }
    }
}

// ---------------------------------------------------------------------------
// Quadrant-pipelined BMx256 GEMM, TWO barriers per K-tile.
// C = A * B^T, B row-major [N][K].
// All 4 quadrants of tile t read from stable buffers, so reads are issued a
// full quadrant (or more) before their consuming MFMA -> every MFMA cluster
// is zero-wait and ds_reads execute on the LDS pipe while the matrix pipe
// drains the previous cluster (breaks the [all-read][all-MFMA] convoy that
// held r1-r4 at 32-37% MfmaUtil).
// Per K-tile t:
//   issue rd b23(t), rd aHi(t); stageA(t+1)   (A(t-1) reads done pre-barend(t-1))
//   MFMA Q1(aLo.b01)  [operands read in prev tile tail]
//   MFMA Q2(aLo.b23)  [b23 had Q1 to land]
//   bar_mid           (all waves consumed b01/b23(t) -> B buf reusable)
//   stageB(t+2)
//   MFMA Q3(aHi.b01)  [aHi had Q1+Q2 to land]
//   vmcnt(4) [retires A(t+1),B(t+1); leaves B(t+2)]  (0 at tail)
//   bar_end           (A(t+1)/B(t+1) visible to all)
//   issue rd aLo(t+1), rd b01(t+1) from flipped buffers
//   MFMA Q4(aHi.b23)  [regs]
// Stage order A-before-B makes the oldest-first vmcnt retire exactly right
// (holds for LA=1 and LA=2: B stages are always 4 loads).
// Epilogue ni-innermost (write-combining, r3-proven: WRITE 100->65.5 MB).
// ---------------------------------------------------------------------------
template <int MODE, int BM, int N, int K, typename TO>
__global__ __launch_bounds__(512, 2) void gemm8p(const bf16* __restrict__ A,
                                                 const bf16* __restrict__ Bm,
                                                 const float* __restrict__ bias,
                                                 TO* __restrict__ outp,
                                                 int Mt) {
    static_assert(BM == 256 || BM == 128);
    constexpr int MR   = BM / 32;        // m-frags per wave (8 or 4)
    constexpr int MR2  = MR / 2;
    constexpr int ABUF = BM * 128;       // bytes per A buffer
    constexpr int BBUF = 256 * 128;      // 32 KB per B buffer
    constexpr int HALF_A = ABUF / 2;
    constexpr int HALF_B = BBUF / 2;     // 16 KB
    constexpr int LA = BM / 128;         // A global_load_lds per thread per half
    constexpr int NT = K / 64;
    static_assert(NT % 2 == 0 && NT >= 4);

    __shared__ __align__(16) char lds[2 * ABUF + 2 * BBUF];

    const int tid  = threadIdx.x;
    const int lane = tid & 63;
    const int wave = tid >> 6;
    const int wr = wave >> 2;            // 0..1
    const int wc = wave & 3;             // 0..3
    const int quad = lane >> 4, l15 = lane & 15;

    // grid: m-fastest rasterization + bijective XCD chunk swizzle
    constexpr int Nt = N / 256;
    const int nwg = Mt * Nt;
    int b = blockIdx.x;
    if ((nwg & 7) == 0) { const int cpx = nwg >> 3; b = (b & 7) * cpx + (b >> 3); }
    const int m_idx = b % Mt;
    const int n_idx = b / Mt;
    const int m0 = m_idx * BM;
    const int n0 = n_idx * 256;

    // swizzled lane offset for fragment ds_read_b128 (within 1024B subtile),
    // plus hoisted per-wave bases so each ds_read is base+immediate (VALU trim)
    const int loff = (l15 * 64 + quad * 16) ^ ((l15 >> 3) << 5);
    const int aol = wr * (MR * 2048) + loff;
    const int bol = wc * 8192 + loff;

    char* const Ab0 = lds;
    char* const Ab1 = lds + ABUF;
    char* const Bb0 = lds + 2 * ABUF;
    char* const Bb1 = lds + 2 * ABUF + BBUF;

    // staging coords: linear LDS chunk s -> inverse-swizzled global (row,k)
    int rowS[2], klS[2];
#pragma unroll
    for (int l = 0; l < 2; ++l) {
        const int s = l * 512 + tid;
        const int c = s & 63;                         // 16B chunk in subtile
        const int e = c ^ (((c >> 5) & 1) << 1);      // unswizzle
        rowS[l] = ((s >> 7) << 4) + (e >> 2);
        klS[l]  = ((s >> 6) & 1) * 32 + (e & 3) * 8;
    }
    const bf16* pa[2]; const bf16* pb[2];
#pragma unroll
    for (int l = 0; l < 2; ++l) {
        pa[l] = A  + (size_t)(m0 + rowS[l]) * K + klS[l];
        pb[l] = Bm + (size_t)(n0 + rowS[l]) * K + klS[l];
    }

    auto stageA = [&](char* dst, int h, int kt) {
#pragma unroll
        for (int l = 0; l < LA; ++l)
            async16(dst + h * HALF_A + (l * 512 + tid) * 16,
                    pa[l] + (size_t)h * (BM / 2) * K + (size_t)kt * 64);
    };
    auto stageB = [&](char* dst, int h, int kt) {
#pragma unroll
        for (int l = 0; l < 2; ++l)
            async16(dst + h * HALF_B + (l * 512 + tid) * 16,
                    pb[l] + (size_t)h * 128 * K + (size_t)kt * 64);
    };
    auto ldA = [&](const char* abase, int mi_g, int ks) -> bf16x8 {
        return __builtin_bit_cast(bf16x8,
            *(const u16x8*)(abase + aol + (((mi_g) * 2 + ks) << 10)));
    };
    auto ldB = [&](const char* bbase, int ni, int ks) -> bf16x8 {
        return __builtin_bit_cast(bf16x8,
            *(const u16x8*)(bbase + bol + (((ni) * 2 + ks) << 10)));
    };

    f32x4 acc[MR][4];
#pragma unroll
    for (int i = 0; i < MR; ++i)
#pragma unroll
        for (int j = 0; j < 4; ++j) acc[i][j] = {0.f, 0.f, 0.f, 0.f};
    bf16x8 aL[MR2][2], aH[MR2][2], b0f[2][2], b2f[2][2];

    // prologue: A(0), B(0), B(1); vmcnt(4) retires A(0)+B(0), leaves B(1)
    stageA(Ab0, 0, 0); stageA(Ab0, 1, 0);
    stageB(Bb0, 0, 0); stageB(Bb0, 1, 0);
    stageB(Bb1, 0, 1); stageB(Bb1, 1, 1);
    asm volatile("s_waitcnt vmcnt(4)" ::: "memory");
    __builtin_amdgcn_s_barrier();
    asm volatile("" ::: "memory");
#pragma unroll
    for (int mi = 0; mi < MR2; ++mi)
#pragma unroll
        for (int ks = 0; ks < 2; ++ks) aL[mi][ks] = ldA(Ab0, mi, ks);
#pragma unroll
    for (int ni = 0; ni < 2; ++ni)
#pragma unroll
        for (int ks = 0; ks < 2; ++ks) b0f[ni][ks] = ldB(Bb0, ni, ks);

#define FENCE() asm volatile("" ::: "memory")
#define MFMA_Q(AR, NI0, AF, BF)                                                 \
    __builtin_amdgcn_s_setprio(1);                                              \
    _Pragma("unroll") for (int mi = 0; mi < MR2; ++mi)                          \
    _Pragma("unroll") for (int ni = 0; ni < 2; ++ni)                            \
    _Pragma("unroll") for (int ks = 0; ks < 2; ++ks)                            \
        acc[(AR) + mi][(NI0) + ni] = __builtin_amdgcn_mfma_f32_16x16x32_bf16(   \
            AF[mi][ks], BF[ni][ks], acc[(AR) + mi][(NI0) + ni], 0, 0, 0);       \
    __builtin_amdgcn_s_setprio(0);

#define KTILE(T, AB, BB, AN, BN)                                                \
    {                                                                           \
        const int t_ = (T);                                                     \
        /* issue-early reads for Q2/Q3; stage A(t+1) */                         \
        _Pragma("unroll") for (int ni = 0; ni < 2; ++ni)                        \
        _Pragma("unroll") for (int ks = 0; ks < 2; ++ks)                        \
            b2f[ni][ks] = ldB(BB, 2 + ni, ks);                                  \
        _Pragma("unroll") for (int mi = 0; mi < MR2; ++mi)                      \
        _Pragma("unroll") for (int ks = 0; ks < 2; ++ks)                        \
            aH[mi][ks] = ldA(AB, MR2 + mi, ks);                                 \
        if (t_ + 1 < NT) { stageA(AN, 0, t_ + 1); stageA(AN, 1, t_ + 1); }      \
        MFMA_Q(0, 0, aL, b0f)      /* Q1: regs from prev tile tail */           \
        MFMA_Q(0, 2, aL, b2f)      /* Q2: b23 had Q1 to land */                 \
        FENCE(); __builtin_amdgcn_s_barrier(); FENCE();   /* bar_mid */         \
        if (t_ + 2 < NT) { stageB(BB, 0, t_ + 2); stageB(BB, 1, t_ + 2); }      \
        MFMA_Q(MR2, 0, aH, b0f)    /* Q3: aHi had Q1+Q2 to land */              \
        if (t_ + 2 < NT) { asm volatile("s_waitcnt vmcnt(4)" ::: "memory"); }   \
        else             { asm volatile("s_waitcnt vmcnt(0)" ::: "memory"); }   \
        FENCE(); __builtin_amdgcn_s_barrier(); FENCE();   /* bar_end */         \
        if (t_ + 1 < NT) {                                                      \
            _Pragma("unroll") for (int mi = 0; mi < MR2; ++mi)                  \
            _Pragma("unroll") for (int ks = 0; ks < 2; ++ks)                    \
                aL[mi][ks] = ldA(AN, mi, ks);                                   \
            _Pragma("unroll") for (int ni = 0; ni < 2; ++ni)                    \
            _Pragma("unroll") for (int ks = 0; ks < 2; ++ks)                    \
                b0f[ni][ks] = ldB(BN, ni, ks);                                  \
        }                                                                       \
        MFMA_Q(MR2, 2, aH, b2f)    /* Q4: regs */                               \
    }

#pragma unroll 1
    for (int t = 0; t < NT; t += 2) {
        KTILE(t,     Ab0, Bb0, Ab1, Bb1)
        KTILE(t + 1, Ab1, Bb1, Ab0, Bb0)
    }
#undef KTILE
#undef MFMA_Q
#undef FENCE

    // epilogue: D row = quad*4 + r, col = l15 (verified m89/m91 mapping)
    // ni-innermost: 4 consecutive stores complete one 128B line per wave-row.
    float bv[4];
#pragma unroll
    for (int ni = 0; ni < 4; ++ni) bv[ni] = bias[n0 + wc * 64 + ni * 16 + l15];
#pragma unroll
    for (int mi = 0; mi < MR; ++mi) {
        const int mrow = m0 + wr * (MR * 16) + mi * 16 + quad * 4;
#pragma unroll
        for (int r = 0; r < 4; ++r) {
            TO* rowp = outp + (size_t)(mrow + r) * N + n0 + wc * 64 + l15;
#pragma unroll
            for (int ni = 0; ni < 4; ++ni) {
                float v = acc[mi][ni][r] + bv[ni];
                if constexpr (MODE == EP_SIGMOID) v = 1.f / (1.f + __expf(-v));
                if constexpr (MODE == EP_RELU)    v = v > 0.f ? v : 0.f;
                if constexpr (std::is_same_v<TO, bf16>)
                    rowp[ni * 16] = __float2bfloat16(v);
                else
                    rowp[ni * 16] = v;
            }
        }
    }
}

// phase 1: per-chunk affine coefficients  buf_out = P*buf_in + Q
// 4 elems/thread, vectorized 8B loads (G13); CH=128 -> 1024 blocks (occupancy)
template <typename XT>
__global__ __launch_bounds__(256) void scan_p1(const XT* __restrict__ x,
                                               const bf16* __restrict__ decay,
                                               float* __restrict__ P,
                                               float* __restrict__ Q) {
    const int bc = blockIdx.x;           // b*CH + c
    const int c = bc & (CH - 1);
    const int b = bc / CH;
    const int i = threadIdx.x * 4;
    size_t idx = ((size_t)(b * Sdim + c * CL)) * Idim + i;
    float p[4] = {1.f, 1.f, 1.f, 1.f};
    float q[4] = {0.f, 0.f, 0.f, 0.f};
#pragma unroll 4
    for (int j = 0; j < CL; ++j) {
        float d[4], xx[4];
        ld4(decay + idx, d);
        ld4(x + idx, xx);
#pragma unroll
        for (int k = 0; k < 4; ++k) {
            q[k] = q[k] * d[k] + (1.f - d[k]) * xx[k];
            p[k] *= d[k];
        }
        idx += Idim;
    }
    *(float4*)(P + (size_t)bc * Idim + i) = {p[0], p[1], p[2], p[3]};
    *(float4*)(Q + (size_t)bc * Idim + i) = {q[0], q[1], q[2], q[3]};
}

// phase 2: sequential combine across chunks (tiny)
__global__ __launch_bounds__(256) void scan_p2(const float* __restrict__ P,
                                               const float* __restrict__ Q,
                                               float* __restrict__ buf0,
                                               int G) {
    const int g = blockIdx.x * 256 + threadIdx.x;
    const int b = g >> 10;
    const int i = g & (Idim - 1);
    if (b >= G) return;
    float buf = 0.f;
    for (int c = 0; c < CH; ++c) {
        const size_t o = ((size_t)(b * CH + c)) * Idim + i;
        buf0[o] = buf;
        buf = P[o] * buf + Q[o];
    }
}

// phase 3: replay with correct init, write combined = x*d + buf (bf16)
// 4 elems/thread, vectorized loads + 8B stores
template <typename XT>
__global__ __launch_bounds__(256) void scan_p3(const XT* __restrict__ x,
                                               const bf16* __restrict__ decay,
                                               const float* __restrict__ buf0,
                                               bf16* __restrict__ comb) {
    const int bc = blockIdx.x;
    const int c = bc & (CH - 1);
    const int b = bc / CH;
    const int i = threadIdx.x * 4;
    size_t idx = ((size_t)(b * Sdim + c * CL)) * Idim + i;
    float buf[4];
    {
        const float4 v = *(const float4*)(buf0 + (size_t)bc * Idim + i);
        buf[0] = v.x; buf[1] = v.y; buf[2] = v.z; buf[3] = v.w;
    }
#pragma unroll 4
    for (int j = 0; j < CL; ++j) {
        float d[4], xx[4];
        ld4(decay + idx, d);
        ld4(x + idx, xx);
        ushort4 o;
#pragma unroll
        for (int k = 0; k < 4; ++k)
            buf[k] = buf[k] * d[k] + (1.f - d[k]) * xx[k];
        o.x = __bfloat16_as_ushort(__float2bfloat16(xx[0] * d[0] + buf[0]));
        o.y = __bfloat16_as_ushort(__float2bfloat16(xx[1] * d[1] + buf[1]));
        o.z = __bfloat16_as_ushort(__float2bfloat16(xx[2] * d[2] + buf[2]));
        o.w = __bfloat16_as_ushort(__float2bfloat16(xx[3] * d[3] + buf[3]));
        *(ushort4*)(comb + idx) = o;
        idx += Idim;
    }
}

extern "C" void kernel_launch(void* const* d_in, const int* in_sizes, int n_in,
                              void* d_out, int out_size, void* d_ws, size_t ws_size,
                              hipStream_t stream) {
    const float* x  = (const float*)d_in[0];
    const float* W1 = (const float*)d_in[1];
    const float* b1 = (const float*)d_in[2];
    const float* W2 = (const float*)d_in[3];
    const float* b2 = (const float*)d_in[4];
    const float* Wg = (const float*)d_in[5];
    const float* bg = (const float*)d_in[6];
    float* out = (float*)d_out;                       // output is f32

    const dim3 blk(256);
    const dim3 blk512(512);

    const size_t nW1 = (size_t)Hdim * Idim;
    const size_t nW2 = (size_t)Odim * Hdim;
    const size_t nWg = (size_t)Idim * Idim;
    const size_t wCopies = (nW1 + nW2 + nWg) * 2;     // 18.9 MB

    const size_t xbB   = (size_t)Sdim * Idim * 2;     // per-batch bf16 x: 4 MB
    const size_t dB    = xbB;                         // decay: 4 MB
    const size_t cmbB  = xbB;                         // comb: 4 MB
    const size_t pB    = (size_t)CH * Idim * 4;       // 512 KB
    const size_t perBatch = xbB + dB + cmbB + 3 * pB; // 13.5 MB

    int G = 0;                                         // 0 = fallback mode
    if (ws_size >= wCopies + 8 * perBatch) G = 8;
    else if (ws_size >= wCopies + 4 * perBatch) G = 4;
    else if (ws_size >= wCopies + 2 * perBatch) G = 2;
    else if (ws_size >= wCopies + 1 * perBatch) G = 1;

    if (G > 0) {
        // ---------- fast path: bf16 copies + quadrant-pipelined GEMMs ----------
        char* p = (char*)d_ws;
        bf16* W1b = (bf16*)p;  p += nW1 * 2;
        bf16* W2b = (bf16*)p;  p += nW2 * 2;
        bf16* Wgb = (bf16*)p;  p += nWg * 2;
        bf16*  xb   = (bf16*)p;
        bf16*  decay= (bf16*)(p + (size_t)G * xbB);
        bf16*  comb = (bf16*)(p + (size_t)G * (xbB + dB));
        float* P    = (float*)(p + (size_t)G * (xbB + dB + cmbB));
        float* Q    = (float*)(p + (size_t)G * (xbB + dB + cmbB + pB));
        float* buf0 = (float*)(p + (size_t)G * (xbB + dB + cmbB + 2 * pB));
        bf16*  hid  = xb;                 // reuses xb+decay (G*8MB) after scan
        const int chunk_rows = G * 1024;  // hid = chunk_rows*Hdim*2 = G*8MB

        cvt_f32_bf16<<<(int)(nW1 / 1024), blk, 0, stream>>>(W1, W1b, (int)nW1);
        cvt_f32_bf16<<<(int)(nW2 / 1024), blk, 0, stream>>>(W2, W2b, (int)nW2);
        cvt_f32_bf16<<<(int)(nWg / 1024), blk, 0, stream>>>(Wg, Wgb, (int)nWg);

        for (int b0 = 0; b0 < Bdim; b0 += G) {
            const float* xg = x + (size_t)b0 * Sdim * Idim;
            const int rowsG = G * Sdim;
            const int nXg = rowsG * Idim;

            cvt_f32_bf16<<<nXg / 1024, blk, 0, stream>>>(xg, xb, nXg);

            gemm8p<EP_SIGMOID, 256, Idim, Idim, bf16>
                <<<(rowsG / 256) * (Idim / 256), blk512, 0, stream>>>(
                    xb, Wgb, bg, decay, rowsG / 256);

            scan_p1<bf16><<<G * CH, blk, 0, stream>>>(xb, decay, P, Q);
            scan_p2<<<G * Idim / 256, blk, 0, stream>>>(P, Q, buf0, G);
            scan_p3<bf16><<<G * CH, blk, 0, stream>>>(xb, decay, buf0, comb);

            for (int r0 = 0; r0 < rowsG; r0 += chunk_rows) {
                const int rows = (rowsG - r0 < chunk_rows) ? rowsG - r0 : chunk_rows;
                gemm8p<EP_RELU, 256, Hdim, Idim, bf16>
                    <<<(rows / 256) * (Hdim / 256), blk512, 0, stream>>>(
                        comb + (size_t)r0 * Idim, W1b, b1, hid, rows / 256);
                gemm8p<EP_BIAS, 128, Odim, Hdim, float>
                    <<<(rows / 128) * (Odim / 256), blk512, 0, stream>>>(
                        hid, W2b, b2, out + (size_t)(b0 * Sdim + r0) * Odim, rows / 128);
            }
        }
    } else {
        // ---------- fallback: no copies, in-register f32->bf16 ----------
        char* p = (char*)d_ws;
        bf16*  decay= (bf16*)p;
        bf16*  comb = (bf16*)(p + dB);
        float* P    = (float*)(p + dB + cmbB);
        float* Q    = (float*)(p + dB + cmbB + pB);
        float* buf0 = (float*)(p + dB + cmbB + 2 * pB);
        char*  hp   = p + dB + cmbB + 3 * pB;
        size_t rem  = (ws_size > (size_t)(hp - (char*)d_ws))
                        ? ws_size - (size_t)(hp - (char*)d_ws) : 0;
        int chunk_rows = (int)((rem / ((size_t)Hdim * 2)) / 128) * 128;
        if (chunk_rows < 128) chunk_rows = 128;
        if (chunk_rows > Sdim) chunk_rows = Sdim;
        bf16* hid = (bf16*)hp;

        for (int b0 = 0; b0 < Bdim; ++b0) {
            const float* xg = x + (size_t)b0 * Sdim * Idim;

            gemm_bt<EP_SIGMOID, Idim, Idim, float, float, bf16>
                <<<(Idim / 128) * (Sdim / 128), blk, 0, stream>>>(
                    xg, Wg, bg, decay, Sdim / 128);

            scan_p1<float><<<CH, blk, 0, stream>>>(xg, decay, P, Q);
            scan_p2<<<Idim / 256, blk, 0, stream>>>(P, Q, buf0, 1);
            scan_p3<float><<<CH, blk, 0, stream>>>(xg, decay, buf0, comb);

            for (int r0 = 0; r0 < Sdim; r0 += chunk_rows) {
                const int rows = (Sdim - r0 < chunk_rows) ? Sdim - r0 : chunk_rows;
                gemm_bt<EP_RELU, Hdim, Idim, bf16, float, bf16>
                    <<<(Hdim / 128) * (rows / 128), blk, 0, stream>>>(
                        comb + (size_t)r0 * Idim, W1, b1, hid, rows / 128);
                gemm_bt<EP_BIAS, Odim, Hdim, bf16, float, float>
                    <<<(Odim / 128) * (rows / 128), blk, 0, stream>>>(
                        hid, W2, b2, out + (size_t)(b0 * Sdim + r0) * Odim, rows / 128);
            }
        }
    }
}